// Round 11
// baseline (453.383 us; speedup 1.0000x reference)
//
#include <hip/hip_runtime.h>
#include <hip/hip_bf16.h>
#include <hip/hip_cooperative_groups.h>

namespace cg = cooperative_groups;

#define F_IN 512
#define NCLS 64
#define SCAN_BLK 512

typedef __attribute__((ext_vector_type(8))) short short8;
typedef __attribute__((ext_vector_type(4))) float f32x4;

static __device__ __forceinline__ short bf16_of(float f) {
    __hip_bfloat16 h = __float2bfloat16(f);
    short s;
    __builtin_memcpy(&s, &h, 2);
    return s;
}
static __device__ __forceinline__ float b2f(short s) {
    unsigned u = ((unsigned)(unsigned short)s) << 16;
    float f;
    __builtin_memcpy(&f, &u, 4);
    return f;
}

// ---- shared device helpers (used by both paths) ----

static __device__ __forceinline__ void wconvert_elem(const float* __restrict__ W,
                                                     short* __restrict__ Wb, int t) {
    int c = t >> 10;
    int kk = (t >> 6) & 15;
    int l = t & 63;
    short8 v;
#pragma unroll
    for (int j = 0; j < 8; ++j) {
        v[j] = bf16_of(W[(size_t)(kk * 32 + (l >> 4) * 8 + j) * NCLS + c * 16 + (l & 15)]);
    }
    reinterpret_cast<short8*>(Wb)[t] = v;
}

// gemm tile body: 128 rows/tile (4 waves x 32 rows), g = bf16(x @ W) UNSCALED
static __device__ __forceinline__ void gemm_tile(const float* __restrict__ x,
                                                 const short8* __restrict__ wb8,
                                                 short* __restrict__ g, int n,
                                                 int tile, int tid) {
    const int wave = tid >> 6;
    const int lane = tid & 63;
    const int rowTile = tile * 128 + wave * 32;

    int r0 = rowTile + (lane & 15);
    int r1 = r0 + 16;
    if (r0 > n - 1) r0 = n - 1;
    if (r1 > n - 1) r1 = n - 1;
    const float* xr0 = x + (size_t)r0 * F_IN + ((lane >> 4) * 8);
    const float* xr1 = x + (size_t)r1 * F_IN + ((lane >> 4) * 8);

    f32x4 acc[2][4];
#pragma unroll
    for (int h = 0; h < 2; ++h)
#pragma unroll
        for (int c = 0; c < 4; ++c) acc[h][c] = {0.f, 0.f, 0.f, 0.f};

#pragma unroll 4
    for (int kk = 0; kk < 16; ++kk) {
        float4 p0 = *reinterpret_cast<const float4*>(xr0 + kk * 32);
        float4 p1 = *reinterpret_cast<const float4*>(xr0 + kk * 32 + 4);
        float4 q0 = *reinterpret_cast<const float4*>(xr1 + kk * 32);
        float4 q1 = *reinterpret_cast<const float4*>(xr1 + kk * 32 + 4);
        short8 a0, a1;
        a0[0] = bf16_of(p0.x); a0[1] = bf16_of(p0.y);
        a0[2] = bf16_of(p0.z); a0[3] = bf16_of(p0.w);
        a0[4] = bf16_of(p1.x); a0[5] = bf16_of(p1.y);
        a0[6] = bf16_of(p1.z); a0[7] = bf16_of(p1.w);
        a1[0] = bf16_of(q0.x); a1[1] = bf16_of(q0.y);
        a1[2] = bf16_of(q0.z); a1[3] = bf16_of(q0.w);
        a1[4] = bf16_of(q1.x); a1[5] = bf16_of(q1.y);
        a1[6] = bf16_of(q1.z); a1[7] = bf16_of(q1.w);
        short8 b0 = wb8[(0 * 16 + kk) * 64 + lane];
        short8 b1 = wb8[(1 * 16 + kk) * 64 + lane];
        short8 b2 = wb8[(2 * 16 + kk) * 64 + lane];
        short8 b3 = wb8[(3 * 16 + kk) * 64 + lane];
        acc[0][0] = __builtin_amdgcn_mfma_f32_16x16x32_bf16(a0, b0, acc[0][0], 0, 0, 0);
        acc[0][1] = __builtin_amdgcn_mfma_f32_16x16x32_bf16(a0, b1, acc[0][1], 0, 0, 0);
        acc[0][2] = __builtin_amdgcn_mfma_f32_16x16x32_bf16(a0, b2, acc[0][2], 0, 0, 0);
        acc[0][3] = __builtin_amdgcn_mfma_f32_16x16x32_bf16(a0, b3, acc[0][3], 0, 0, 0);
        acc[1][0] = __builtin_amdgcn_mfma_f32_16x16x32_bf16(a1, b0, acc[1][0], 0, 0, 0);
        acc[1][1] = __builtin_amdgcn_mfma_f32_16x16x32_bf16(a1, b1, acc[1][1], 0, 0, 0);
        acc[1][2] = __builtin_amdgcn_mfma_f32_16x16x32_bf16(a1, b2, acc[1][2], 0, 0, 0);
        acc[1][3] = __builtin_amdgcn_mfma_f32_16x16x32_bf16(a1, b3, acc[1][3], 0, 0, 0);
    }

    const int col = lane & 15;
#pragma unroll
    for (int h = 0; h < 2; ++h) {
        const int rbase = rowTile + h * 16 + (lane >> 4) * 4;
#pragma unroll
        for (int j = 0; j < 4; ++j) {
            int r = rbase + j;
            if (r < n) {
                short* go = g + (size_t)r * NCLS + col;
                go[0]  = bf16_of(acc[h][0][j]);
                go[16] = bf16_of(acc[h][1][j]);
                go[32] = bf16_of(acc[h][2][j]);
                go[48] = bf16_of(acc[h][3][j]);
            }
        }
    }
}

// aggregate body for a 32-node virtual block (4 waves x 8 nodes); g unscaled,
// per-edge dinv[src], self term dinv[node]^2, bias + log_softmax.
static __device__ __forceinline__ void agg_vblock(const short8* __restrict__ g8,
                                                  const float* __restrict__ dinv,
                                                  const float* __restrict__ bvec,
                                                  const int* __restrict__ off,
                                                  const int* __restrict__ parts,
                                                  const int* __restrict__ eidx,
                                                  float* __restrict__ out, int n,
                                                  int vb, int tid) {
    const int wave = tid >> 6;
    const int lane = tid & 63;
    const int sgrp = lane >> 3;
    const int li = lane & 7;
    const int node = (vb * 4 + wave) * 8 + sgrp;
    if (node >= n) return;

    const int s0 = off[node] + parts[node >> 9];
    const int np1 = node + 1;
    const int s1 = off[np1] + parts[(np1 == n ? n - 1 : np1) >> 9];

    const float dn = dinv[node];

    float acc[8];
    {
        short8 v = g8[(size_t)node * 8 + li];
#pragma unroll
        for (int c = 0; c < 8; ++c) acc[c] = b2f(v[c]) * dn;  // self: g*dinv
    }

    int t = s0;
    for (; t + 4 <= s1; t += 4) {
        int sa = eidx[t], sb = eidx[t + 1], sc = eidx[t + 2], sd = eidx[t + 3];
        float da = dinv[sa], db = dinv[sb], dc = dinv[sc], dd = dinv[sd];
        short8 va = g8[(size_t)sa * 8 + li];
        short8 vb4 = g8[(size_t)sb * 8 + li];
        short8 vc = g8[(size_t)sc * 8 + li];
        short8 vd = g8[(size_t)sd * 8 + li];
#pragma unroll
        for (int c = 0; c < 8; ++c)
            acc[c] += (b2f(va[c]) * da + b2f(vb4[c]) * db) +
                      (b2f(vc[c]) * dc + b2f(vd[c]) * dd);
    }
    for (; t < s1; ++t) {
        int sa = eidx[t];
        float da = dinv[sa];
        short8 va = g8[(size_t)sa * 8 + li];
#pragma unroll
        for (int c = 0; c < 8; ++c) acc[c] += b2f(va[c]) * da;
    }

    const float4 bb0 = reinterpret_cast<const float4*>(bvec)[li * 2];
    const float4 bb1 = reinterpret_cast<const float4*>(bvec)[li * 2 + 1];
    float v[8];
    v[0] = acc[0] * dn + bb0.x; v[1] = acc[1] * dn + bb0.y;
    v[2] = acc[2] * dn + bb0.z; v[3] = acc[3] * dn + bb0.w;
    v[4] = acc[4] * dn + bb1.x; v[5] = acc[5] * dn + bb1.y;
    v[6] = acc[6] * dn + bb1.z; v[7] = acc[7] * dn + bb1.w;

    float m = v[0];
#pragma unroll
    for (int c = 1; c < 8; ++c) m = fmaxf(m, v[c]);
#pragma unroll
    for (int o = 1; o < 8; o <<= 1) m = fmaxf(m, __shfl_xor(m, o));

    float ex = 0.f;
#pragma unroll
    for (int c = 0; c < 8; ++c) ex += __expf(v[c] - m);
#pragma unroll
    for (int o = 1; o < 8; o <<= 1) ex += __shfl_xor(ex, o);
    const float lg = m + __logf(ex);

    float4 r0, r1;
    r0.x = v[0] - lg; r0.y = v[1] - lg; r0.z = v[2] - lg; r0.w = v[3] - lg;
    r1.x = v[4] - lg; r1.y = v[5] - lg; r1.z = v[6] - lg; r1.w = v[7] - lg;
    float4* o4 = reinterpret_cast<float4*>(out + (size_t)node * NCLS);
    o4[li * 2] = r0;
    o4[li * 2 + 1] = r1;
}

// ================= cooperative fused kernel =================
__global__ __launch_bounds__(256) void fused(
    const float* __restrict__ x, const float* __restrict__ W,
    const float* __restrict__ bvec,
    const int* __restrict__ src, const int* __restrict__ dst, int n, int e,
    short* __restrict__ g, short* __restrict__ Wb, float* __restrict__ dinv,
    int* __restrict__ cnt, int* __restrict__ off, int* __restrict__ parts,
    unsigned short* __restrict__ rank, int* __restrict__ eidx,
    float* __restrict__ out) {
    cg::grid_group grid = cg::this_grid();
    const int bid = blockIdx.x;
    const int nb = gridDim.x;
    const int tid = threadIdx.x;
    const int gtid = bid * 256 + tid;
    const int gstride = nb * 256;

    __shared__ int sdata[256];

    // ---- P0: wconvert + zero cnt ----
    if (gtid < 4096) wconvert_elem(W, Wb, gtid);
    for (int i = gtid; i < n; i += gstride) cnt[i] = 0;

    grid.sync();

    // ---- P1: deg_count (1/4 of blocks) || gemm (3/4) ----
    const int DEG = nb >> 2;
    if (bid < DEG) {
        const int S = DEG * 256;
        int i = bid * 256 + tid;
        for (; i + 3 * S < e; i += 4 * S) {
            int d0 = dst[i], d1 = dst[i + S], d2 = dst[i + 2 * S], d3 = dst[i + 3 * S];
            rank[i]         = (unsigned short)atomicAdd(&cnt[d0], 1);
            rank[i + S]     = (unsigned short)atomicAdd(&cnt[d1], 1);
            rank[i + 2 * S] = (unsigned short)atomicAdd(&cnt[d2], 1);
            rank[i + 3 * S] = (unsigned short)atomicAdd(&cnt[d3], 1);
        }
        for (; i < e; i += S) rank[i] = (unsigned short)atomicAdd(&cnt[dst[i]], 1);
    } else {
        const int nTiles = (n + 127) / 128;
        const short8* wb8 = reinterpret_cast<const short8*>(Wb);
        for (int tile = bid - DEG; tile < nTiles; tile += nb - DEG)
            gemm_tile(x, wb8, g, n, tile, tid);
    }

    grid.sync();

    // ---- P2: scan1 — 512-elem chunks, 2 elems/thread, + dinv ----
    const int nChunks = (n + 511) / 512;
    for (int chunk = bid; chunk < nChunks; chunk += nb) {
        int base = chunk * 512;
        int i0 = base + 2 * tid;
        int i1 = i0 + 1;
        int v0 = (i0 < n) ? cnt[i0] : 0;
        int v1 = (i1 < n) ? cnt[i1] : 0;
        if (i0 < n) dinv[i0] = rsqrtf(1.0f + (float)v0);
        if (i1 < n) dinv[i1] = rsqrtf(1.0f + (float)v1);
        int ps = v0 + v1;
        sdata[tid] = ps;
        __syncthreads();
#pragma unroll
        for (int d = 1; d < 256; d <<= 1) {
            int t2 = (tid >= d) ? sdata[tid - d] : 0;
            __syncthreads();
            sdata[tid] += t2;
            __syncthreads();
        }
        int incl = sdata[tid];
        int ex = incl - ps;
        if (i0 < n) off[i0] = ex;
        if (i1 < n) off[i1] = ex + v0;
        if (i1 == n - 1) off[n] = ex + ps;
        else if (i0 == n - 1) off[n] = ex + v0;
        if (tid == 255) parts[chunk] = incl;
        __syncthreads();
    }

    grid.sync();

    // ---- P3: scan2 (block 0) ----
    if (bid == 0) {
        int v = (tid < nChunks) ? parts[tid] : 0;
        sdata[tid] = v;
        __syncthreads();
#pragma unroll
        for (int d = 1; d < 256; d <<= 1) {
            int t2 = (tid >= d) ? sdata[tid - d] : 0;
            __syncthreads();
            sdata[tid] += t2;
            __syncthreads();
        }
        if (tid < nChunks) parts[tid] = sdata[tid] - v;
    }

    grid.sync();

    // ---- P4: fill CSR (no atomics) ----
    for (int i = gtid; i < e; i += gstride) {
        int d = dst[i];
        eidx[off[d] + parts[d >> 9] + (int)rank[i]] = src[i];
    }

    grid.sync();

    // ---- P5: aggregate + bias + log_softmax ----
    {
        const int nVB = (n + 31) / 32;
        const short8* g8 = reinterpret_cast<const short8*>(g);
        for (int vb = bid; vb < nVB; vb += nb)
            agg_vblock(g8, dinv, bvec, off, parts, eidx, out, n, vb, tid);
    }
}

// ================= fallback path (proven round-7/8 kernels) =================

__global__ __launch_bounds__(256) void k_prelude(const float* __restrict__ W,
                                                 short* __restrict__ Wb,
                                                 int* __restrict__ cnt, int n) {
    const int bid = blockIdx.x;
    if (bid < 16) {
        wconvert_elem(W, Wb, bid * 256 + threadIdx.x);
    } else {
        int i = (bid - 16) * 256 + threadIdx.x;
        if (i < n) cnt[i] = 0;
    }
}

__global__ __launch_bounds__(256) void k_deg(const int* __restrict__ dst,
                                             int* __restrict__ cnt,
                                             unsigned short* __restrict__ rank, int e) {
    int base = (blockIdx.x * 256 + threadIdx.x) * 4;
    if (base + 4 <= e) {
        int4 d4 = *reinterpret_cast<const int4*>(dst + base);
        ushort4 r;
        r.x = (unsigned short)atomicAdd(&cnt[d4.x], 1);
        r.y = (unsigned short)atomicAdd(&cnt[d4.y], 1);
        r.z = (unsigned short)atomicAdd(&cnt[d4.z], 1);
        r.w = (unsigned short)atomicAdd(&cnt[d4.w], 1);
        *reinterpret_cast<ushort4*>(rank + base) = r;
    } else {
        for (int i = base; i < e; ++i)
            rank[i] = (unsigned short)atomicAdd(&cnt[dst[i]], 1);
    }
}

__global__ __launch_bounds__(SCAN_BLK) void k_scan1(const int* __restrict__ cnt,
                                                    int* __restrict__ off,
                                                    int* __restrict__ partials,
                                                    float* __restrict__ dinv, int n) {
    __shared__ int s[SCAN_BLK];
    int tid = threadIdx.x;
    int i = blockIdx.x * SCAN_BLK + tid;
    int v = (i < n) ? cnt[i] : 0;
    if (i < n) dinv[i] = rsqrtf(1.0f + (float)v);
    s[tid] = v;
    __syncthreads();
#pragma unroll
    for (int d = 1; d < SCAN_BLK; d <<= 1) {
        int t = (tid >= d) ? s[tid - d] : 0;
        __syncthreads();
        s[tid] += t;
        __syncthreads();
    }
    if (i < n) off[i] = s[tid] - v;
    if (i == n - 1) off[n] = s[tid];
    if (tid == SCAN_BLK - 1) partials[blockIdx.x] = s[tid];
}

__global__ __launch_bounds__(256) void k_scan2(int* __restrict__ partials, int p) {
    __shared__ int s[256];
    int tid = threadIdx.x;
    int v = (tid < p) ? partials[tid] : 0;
    s[tid] = v;
    __syncthreads();
#pragma unroll
    for (int d = 1; d < 256; d <<= 1) {
        int t = (tid >= d) ? s[tid - d] : 0;
        __syncthreads();
        s[tid] += t;
        __syncthreads();
    }
    if (tid < p) partials[tid] = s[tid] - v;
}

__global__ __launch_bounds__(256) void k_fill(const int* __restrict__ src,
                                              const int* __restrict__ dst,
                                              const int* __restrict__ off,
                                              const int* __restrict__ parts,
                                              const unsigned short* __restrict__ rank,
                                              int* __restrict__ eidx, int e) {
    int base = (blockIdx.x * 256 + threadIdx.x) * 4;
    if (base + 4 <= e) {
        int4 s4 = *reinterpret_cast<const int4*>(src + base);
        int4 d4 = *reinterpret_cast<const int4*>(dst + base);
        ushort4 r4 = *reinterpret_cast<const ushort4*>(rank + base);
        eidx[off[d4.x] + parts[d4.x >> 9] + r4.x] = s4.x;
        eidx[off[d4.y] + parts[d4.y >> 9] + r4.y] = s4.y;
        eidx[off[d4.z] + parts[d4.z >> 9] + r4.z] = s4.z;
        eidx[off[d4.w] + parts[d4.w >> 9] + r4.w] = s4.w;
    } else {
        for (int i = base; i < e; ++i)
            eidx[off[dst[i]] + parts[dst[i] >> 9] + rank[i]] = src[i];
    }
}

__global__ __launch_bounds__(256) void k_gemm(const float* __restrict__ x,
                                              const short* __restrict__ Wb,
                                              short* __restrict__ g, int n) {
    gemm_tile(x, reinterpret_cast<const short8*>(Wb), g, n, blockIdx.x, threadIdx.x);
}

__global__ __launch_bounds__(256) void k_agg(const short* __restrict__ g,
                                             const float* __restrict__ dinv,
                                             const float* __restrict__ bvec,
                                             const int* __restrict__ off,
                                             const int* __restrict__ parts,
                                             const int* __restrict__ eidx,
                                             float* __restrict__ out, int n) {
    agg_vblock(reinterpret_cast<const short8*>(g), dinv, bvec, off, parts, eidx,
               out, n, blockIdx.x, threadIdx.x);
}

extern "C" void kernel_launch(void* const* d_in, const int* in_sizes, int n_in,
                              void* d_out, int out_size, void* d_ws, size_t ws_size,
                              hipStream_t stream) {
    const float* x = (const float*)d_in[0];       // [N, 512]
    const float* W = (const float*)d_in[1];       // [512, 64]
    const float* b = (const float*)d_in[2];       // [64]
    const int* edge_index = (const int*)d_in[3];  // [2, E]

    int N = in_sizes[0] / F_IN;
    int E = in_sizes[3] / 2;
    const int* src = edge_index;
    const int* dst = edge_index + E;

    float* out = (float*)d_out;  // [N, 64]

    // workspace layout
    char* ws = (char*)d_ws;
    short* g     = (short*)ws;  ws += (size_t)N * NCLS * 2;   // 12.8 MB bf16
    short* Wb    = (short*)ws;  ws += 4096 * 16;              // 64 KB
    float* dinv  = (float*)ws;  ws += (size_t)N * 4;
    int*   cnt   = (int*)ws;    ws += (size_t)N * 4;
    int*   off   = (int*)ws;    ws += (size_t)(N + 4) * 4;
    int*   parts = (int*)ws;    ws += 1024 * 4;
    unsigned short* rank = (unsigned short*)ws;  ws += (size_t)((E + 7) & ~7) * 2;
    int*   eidx  = (int*)ws;    // E ints

    // ---- try cooperative fused path with a guaranteed-feasible grid ----
    int blocksPerCU = 0;
    hipError_t qerr = hipOccupancyMaxActiveBlocksPerMultiprocessor(
        &blocksPerCU, (const void*)fused, 256, 0);
    int numCU = 0;
    int dev = 0;
    hipGetDevice(&dev);
    hipDeviceGetAttribute(&numCU, hipDeviceAttributeMultiprocessorCount, dev);

    bool coop_ok = false;
    if (qerr == hipSuccess && blocksPerCU > 0 && numCU > 0) {
        long long maxGrid = (long long)blocksPerCU * numCU;
        int grid = (int)(maxGrid > 1024 ? 1024 : maxGrid);
        if (grid >= 32) {
            void* args[] = {(void*)&x, (void*)&W, (void*)&b, (void*)&src, (void*)&dst,
                            (void*)&N, (void*)&E, (void*)&g, (void*)&Wb, (void*)&dinv,
                            (void*)&cnt, (void*)&off, (void*)&parts, (void*)&rank,
                            (void*)&eidx, (void*)&out};
            hipError_t lerr = hipLaunchCooperativeKernel(
                (const void*)fused, dim3(grid), dim3(256), args, 0, stream);
            coop_ok = (lerr == hipSuccess);
        }
    }
    if (coop_ok) return;

    // ---- fallback: proven separated-kernel path ----
    const int nScanBlocks = (N + SCAN_BLK - 1) / SCAN_BLK;
    const int edgeBlocks = (E + 1023) / 1024;

    k_prelude<<<16 + (N + 255) / 256, 256, 0, stream>>>(W, Wb, cnt, N);
    k_deg<<<edgeBlocks, 256, 0, stream>>>(dst, cnt, rank, E);
    k_scan1<<<nScanBlocks, SCAN_BLK, 0, stream>>>(cnt, off, parts, dinv, N);
    k_scan2<<<1, 256, 0, stream>>>(parts, nScanBlocks);
    k_gemm<<<(N + 127) / 128, 256, 0, stream>>>(x, Wb, g, N);
    k_fill<<<edgeBlocks, 256, 0, stream>>>(src, dst, off, parts, rank, eidx, E);
    k_agg<<<(N + 31) / 32, 256, 0, stream>>>(g, dinv, b, off, parts, eidx, out, N);
}

// Round 12
// 236.537 us; speedup vs baseline: 1.9167x; 1.9167x over previous
//
#include <hip/hip_runtime.h>
#include <hip/hip_bf16.h>

#define F_IN 512
#define NCLS 64
#define SCAN_BLK 512
#define DEG_CHUNK 16384

typedef __attribute__((ext_vector_type(8))) short short8;
typedef __attribute__((ext_vector_type(4))) float f32x4;

static __device__ __forceinline__ short bf16_of(float f) {
    __hip_bfloat16 h = __float2bfloat16(f);
    short s;
    __builtin_memcpy(&s, &h, 2);
    return s;
}
static __device__ __forceinline__ float b2f(short s) {
    unsigned u = ((unsigned)(unsigned short)s) << 16;
    float f;
    __builtin_memcpy(&f, &u, 4);
    return f;
}

// ---- shared device helpers ----

static __device__ __forceinline__ void wconvert_elem(const float* __restrict__ W,
                                                     short* __restrict__ Wb, int t) {
    int c = t >> 10;
    int kk = (t >> 6) & 15;
    int l = t & 63;
    short8 v;
#pragma unroll
    for (int j = 0; j < 8; ++j) {
        v[j] = bf16_of(W[(size_t)(kk * 32 + (l >> 4) * 8 + j) * NCLS + c * 16 + (l & 15)]);
    }
    reinterpret_cast<short8*>(Wb)[t] = v;
}

// gemm tile body: 128 rows/tile (4 waves x 32 rows), g = bf16(x @ W) UNSCALED
static __device__ __forceinline__ void gemm_tile(const float* __restrict__ x,
                                                 const short8* __restrict__ wb8,
                                                 short* __restrict__ g, int n,
                                                 int tile, int tid) {
    const int wave = tid >> 6;
    const int lane = tid & 63;
    const int rowTile = tile * 128 + wave * 32;

    int r0 = rowTile + (lane & 15);
    int r1 = r0 + 16;
    if (r0 > n - 1) r0 = n - 1;
    if (r1 > n - 1) r1 = n - 1;
    const float* xr0 = x + (size_t)r0 * F_IN + ((lane >> 4) * 8);
    const float* xr1 = x + (size_t)r1 * F_IN + ((lane >> 4) * 8);

    f32x4 acc[2][4];
#pragma unroll
    for (int h = 0; h < 2; ++h)
#pragma unroll
        for (int c = 0; c < 4; ++c) acc[h][c] = {0.f, 0.f, 0.f, 0.f};

#pragma unroll 4
    for (int kk = 0; kk < 16; ++kk) {
        float4 p0 = *reinterpret_cast<const float4*>(xr0 + kk * 32);
        float4 p1 = *reinterpret_cast<const float4*>(xr0 + kk * 32 + 4);
        float4 q0 = *reinterpret_cast<const float4*>(xr1 + kk * 32);
        float4 q1 = *reinterpret_cast<const float4*>(xr1 + kk * 32 + 4);
        short8 a0, a1;
        a0[0] = bf16_of(p0.x); a0[1] = bf16_of(p0.y);
        a0[2] = bf16_of(p0.z); a0[3] = bf16_of(p0.w);
        a0[4] = bf16_of(p1.x); a0[5] = bf16_of(p1.y);
        a0[6] = bf16_of(p1.z); a0[7] = bf16_of(p1.w);
        a1[0] = bf16_of(q0.x); a1[1] = bf16_of(q0.y);
        a1[2] = bf16_of(q0.z); a1[3] = bf16_of(q0.w);
        a1[4] = bf16_of(q1.x); a1[5] = bf16_of(q1.y);
        a1[6] = bf16_of(q1.z); a1[7] = bf16_of(q1.w);
        short8 b0 = wb8[(0 * 16 + kk) * 64 + lane];
        short8 b1 = wb8[(1 * 16 + kk) * 64 + lane];
        short8 b2 = wb8[(2 * 16 + kk) * 64 + lane];
        short8 b3 = wb8[(3 * 16 + kk) * 64 + lane];
        acc[0][0] = __builtin_amdgcn_mfma_f32_16x16x32_bf16(a0, b0, acc[0][0], 0, 0, 0);
        acc[0][1] = __builtin_amdgcn_mfma_f32_16x16x32_bf16(a0, b1, acc[0][1], 0, 0, 0);
        acc[0][2] = __builtin_amdgcn_mfma_f32_16x16x32_bf16(a0, b2, acc[0][2], 0, 0, 0);
        acc[0][3] = __builtin_amdgcn_mfma_f32_16x16x32_bf16(a0, b3, acc[0][3], 0, 0, 0);
        acc[1][0] = __builtin_amdgcn_mfma_f32_16x16x32_bf16(a1, b0, acc[1][0], 0, 0, 0);
        acc[1][1] = __builtin_amdgcn_mfma_f32_16x16x32_bf16(a1, b1, acc[1][1], 0, 0, 0);
        acc[1][2] = __builtin_amdgcn_mfma_f32_16x16x32_bf16(a1, b2, acc[1][2], 0, 0, 0);
        acc[1][3] = __builtin_amdgcn_mfma_f32_16x16x32_bf16(a1, b3, acc[1][3], 0, 0, 0);
    }

    const int col = lane & 15;
#pragma unroll
    for (int h = 0; h < 2; ++h) {
        const int rbase = rowTile + h * 16 + (lane >> 4) * 4;
#pragma unroll
        for (int j = 0; j < 4; ++j) {
            int r = rbase + j;
            if (r < n) {
                short* go = g + (size_t)r * NCLS + col;
                go[0]  = bf16_of(acc[h][0][j]);
                go[16] = bf16_of(acc[h][1][j]);
                go[32] = bf16_of(acc[h][2][j]);
                go[48] = bf16_of(acc[h][3][j]);
            }
        }
    }
}

// aggregate body for a 32-node virtual block; g unscaled, per-edge dinv[src].
static __device__ __forceinline__ void agg_vblock(const short8* __restrict__ g8,
                                                  const float* __restrict__ dinv,
                                                  const float* __restrict__ bvec,
                                                  const int* __restrict__ off,
                                                  const int* __restrict__ parts,
                                                  const int* __restrict__ eidx,
                                                  float* __restrict__ out, int n,
                                                  int vb, int tid) {
    const int wave = tid >> 6;
    const int lane = tid & 63;
    const int sgrp = lane >> 3;
    const int li = lane & 7;
    const int node = (vb * 4 + wave) * 8 + sgrp;
    if (node >= n) return;

    const int s0 = off[node] + parts[node >> 9];
    const int np1 = node + 1;
    const int s1 = off[np1] + parts[(np1 == n ? n - 1 : np1) >> 9];

    const float dn = dinv[node];

    float acc[8];
    {
        short8 v = g8[(size_t)node * 8 + li];
#pragma unroll
        for (int c = 0; c < 8; ++c) acc[c] = b2f(v[c]) * dn;  // self: g*dinv
    }

    int t = s0;
    for (; t + 4 <= s1; t += 4) {
        int sa = eidx[t], sb = eidx[t + 1], sc = eidx[t + 2], sd = eidx[t + 3];
        float da = dinv[sa], db = dinv[sb], dc = dinv[sc], dd = dinv[sd];
        short8 va = g8[(size_t)sa * 8 + li];
        short8 vb4 = g8[(size_t)sb * 8 + li];
        short8 vc = g8[(size_t)sc * 8 + li];
        short8 vd = g8[(size_t)sd * 8 + li];
#pragma unroll
        for (int c = 0; c < 8; ++c)
            acc[c] += (b2f(va[c]) * da + b2f(vb4[c]) * db) +
                      (b2f(vc[c]) * dc + b2f(vd[c]) * dd);
    }
    for (; t < s1; ++t) {
        int sa = eidx[t];
        float da = dinv[sa];
        short8 va = g8[(size_t)sa * 8 + li];
#pragma unroll
        for (int c = 0; c < 8; ++c) acc[c] += b2f(va[c]) * da;
    }

    const float4 bb0 = reinterpret_cast<const float4*>(bvec)[li * 2];
    const float4 bb1 = reinterpret_cast<const float4*>(bvec)[li * 2 + 1];
    float v[8];
    v[0] = acc[0] * dn + bb0.x; v[1] = acc[1] * dn + bb0.y;
    v[2] = acc[2] * dn + bb0.z; v[3] = acc[3] * dn + bb0.w;
    v[4] = acc[4] * dn + bb1.x; v[5] = acc[5] * dn + bb1.y;
    v[6] = acc[6] * dn + bb1.z; v[7] = acc[7] * dn + bb1.w;

    float m = v[0];
#pragma unroll
    for (int c = 1; c < 8; ++c) m = fmaxf(m, v[c]);
#pragma unroll
    for (int o = 1; o < 8; o <<= 1) m = fmaxf(m, __shfl_xor(m, o));

    float ex = 0.f;
#pragma unroll
    for (int c = 0; c < 8; ++c) ex += __expf(v[c] - m);
#pragma unroll
    for (int o = 1; o < 8; o <<= 1) ex += __shfl_xor(ex, o);
    const float lg = m + __logf(ex);

    float4 r0, r1;
    r0.x = v[0] - lg; r0.y = v[1] - lg; r0.z = v[2] - lg; r0.w = v[3] - lg;
    r1.x = v[4] - lg; r1.y = v[5] - lg; r1.z = v[6] - lg; r1.w = v[7] - lg;
    float4* o4 = reinterpret_cast<float4*>(out + (size_t)node * NCLS);
    o4[li * 2] = r0;
    o4[li * 2 + 1] = r1;
}

// ---------------- prelude: wconvert + zero cnt + zero work counters ----------------
__global__ __launch_bounds__(256) void k_prelude(const float* __restrict__ W,
                                                 short* __restrict__ Wb,
                                                 int* __restrict__ cnt,
                                                 int* __restrict__ ctr, int n) {
    const int bid = blockIdx.x;
    if (bid < 16) {
        wconvert_elem(W, Wb, bid * 256 + threadIdx.x);
    } else {
        if (bid == 16 && threadIdx.x < 8) ctr[threadIdx.x] = 0;
        int i = (bid - 16) * 256 + threadIdx.x;
        if (i < n) cnt[i] = 0;
    }
}

// ---------------- megaX: XCD-partitioned work-stealing {deg} || {gemm} ----------------
// Blocks on XCD 7 prefer the deg pool (atomics issue from 32 CUs only -> isolated
// fabric pressure); all other XCDs prefer gemm tiles (clean L2/fabric). Each side
// falls through to the other pool when its own is drained, so completion and
// correctness do not depend on the xcc read.
__global__ __launch_bounds__(256) void megaX(const float* __restrict__ x,
                                             const short* __restrict__ Wb,
                                             short* __restrict__ g, int n,
                                             const int* __restrict__ dst,
                                             int* __restrict__ cnt,
                                             unsigned short* __restrict__ rank, int e,
                                             int* __restrict__ ctr,
                                             int nDegChunks, int nTiles) {
    __shared__ int s_item;
    const int tid = threadIdx.x;
    unsigned xcc = 0;
    asm volatile("s_getreg_b32 %0, hwreg(HW_REG_XCC_ID)" : "=s"(xcc));
    const bool preferDeg = ((xcc & 7u) == 7u);
    const short8* wb8 = reinterpret_cast<const short8*>(Wb);

#pragma unroll
    for (int pass = 0; pass < 2; ++pass) {
        const bool doDeg = (pass == 0) ? preferDeg : !preferDeg;
        if (doDeg) {
            for (;;) {
                if (tid == 0) s_item = atomicAdd(&ctr[0], 1);
                __syncthreads();
                int c = s_item;
                __syncthreads();
                if (c >= nDegChunks) break;
                const int base0 = c * DEG_CHUNK;
                int endE = base0 + DEG_CHUNK;
                if (endE > e) endE = e;
#pragma unroll
                for (int j = 0; j < DEG_CHUNK / 1024; ++j) {
                    int i = base0 + (j * 256 + tid) * 4;
                    if (i + 4 <= endE) {
                        int4 d4 = *reinterpret_cast<const int4*>(dst + i);
                        ushort4 r;
                        r.x = (unsigned short)atomicAdd(&cnt[d4.x], 1);
                        r.y = (unsigned short)atomicAdd(&cnt[d4.y], 1);
                        r.z = (unsigned short)atomicAdd(&cnt[d4.z], 1);
                        r.w = (unsigned short)atomicAdd(&cnt[d4.w], 1);
                        *reinterpret_cast<ushort4*>(rank + i) = r;
                    } else {
                        for (int k2 = i; k2 < endE; ++k2)
                            rank[k2] = (unsigned short)atomicAdd(&cnt[dst[k2]], 1);
                    }
                }
            }
        } else {
            for (;;) {
                if (tid == 0) s_item = atomicAdd(&ctr[1], 1);
                __syncthreads();
                int t2 = s_item;
                __syncthreads();
                if (t2 >= nTiles) break;
                gemm_tile(x, wb8, g, n, t2, tid);
            }
        }
    }
}

// ---------------- scan kernels (proven R8 versions) ----------------
__global__ __launch_bounds__(SCAN_BLK) void k_scan1(const int* __restrict__ cnt,
                                                    int* __restrict__ off,
                                                    int* __restrict__ partials,
                                                    float* __restrict__ dinv, int n) {
    __shared__ int s[SCAN_BLK];
    int tid = threadIdx.x;
    int i = blockIdx.x * SCAN_BLK + tid;
    int v = (i < n) ? cnt[i] : 0;
    if (i < n) dinv[i] = rsqrtf(1.0f + (float)v);
    s[tid] = v;
    __syncthreads();
#pragma unroll
    for (int d = 1; d < SCAN_BLK; d <<= 1) {
        int t = (tid >= d) ? s[tid - d] : 0;
        __syncthreads();
        s[tid] += t;
        __syncthreads();
    }
    if (i < n) off[i] = s[tid] - v;
    if (i == n - 1) off[n] = s[tid];
    if (tid == SCAN_BLK - 1) partials[blockIdx.x] = s[tid];
}

__global__ __launch_bounds__(256) void k_scan2(int* __restrict__ partials, int p) {
    __shared__ int s[256];
    int tid = threadIdx.x;
    int v = (tid < p) ? partials[tid] : 0;
    s[tid] = v;
    __syncthreads();
#pragma unroll
    for (int d = 1; d < 256; d <<= 1) {
        int t = (tid >= d) ? s[tid - d] : 0;
        __syncthreads();
        s[tid] += t;
        __syncthreads();
    }
    if (tid < p) partials[tid] = s[tid] - v;
}

// ---------------- fill CSR — no atomics, 4 edges/thread ----------------
__global__ __launch_bounds__(256) void k_fill(const int* __restrict__ src,
                                              const int* __restrict__ dst,
                                              const int* __restrict__ off,
                                              const int* __restrict__ parts,
                                              const unsigned short* __restrict__ rank,
                                              int* __restrict__ eidx, int e) {
    int base = (blockIdx.x * 256 + threadIdx.x) * 4;
    if (base + 4 <= e) {
        int4 s4 = *reinterpret_cast<const int4*>(src + base);
        int4 d4 = *reinterpret_cast<const int4*>(dst + base);
        ushort4 r4 = *reinterpret_cast<const ushort4*>(rank + base);
        eidx[off[d4.x] + parts[d4.x >> 9] + r4.x] = s4.x;
        eidx[off[d4.y] + parts[d4.y >> 9] + r4.y] = s4.y;
        eidx[off[d4.z] + parts[d4.z >> 9] + r4.z] = s4.z;
        eidx[off[d4.w] + parts[d4.w >> 9] + r4.w] = s4.w;
    } else {
        for (int i = base; i < e; ++i)
            eidx[off[dst[i]] + parts[dst[i] >> 9] + rank[i]] = src[i];
    }
}

__global__ __launch_bounds__(256) void k_agg(const short* __restrict__ g,
                                             const float* __restrict__ dinv,
                                             const float* __restrict__ bvec,
                                             const int* __restrict__ off,
                                             const int* __restrict__ parts,
                                             const int* __restrict__ eidx,
                                             float* __restrict__ out, int n) {
    agg_vblock(reinterpret_cast<const short8*>(g), dinv, bvec, off, parts, eidx,
               out, n, blockIdx.x, threadIdx.x);
}

extern "C" void kernel_launch(void* const* d_in, const int* in_sizes, int n_in,
                              void* d_out, int out_size, void* d_ws, size_t ws_size,
                              hipStream_t stream) {
    const float* x = (const float*)d_in[0];       // [N, 512]
    const float* W = (const float*)d_in[1];       // [512, 64]
    const float* b = (const float*)d_in[2];       // [64]
    const int* edge_index = (const int*)d_in[3];  // [2, E]

    int N = in_sizes[0] / F_IN;
    int E = in_sizes[3] / 2;
    const int* src = edge_index;
    const int* dst = edge_index + E;

    float* out = (float*)d_out;  // [N, 64]

    // workspace layout
    char* ws = (char*)d_ws;
    short* g     = (short*)ws;  ws += (size_t)N * NCLS * 2;   // 12.8 MB bf16
    short* Wb    = (short*)ws;  ws += 4096 * 16;              // 64 KB
    float* dinv  = (float*)ws;  ws += (size_t)N * 4;
    int*   cnt   = (int*)ws;    ws += (size_t)N * 4;
    int*   ctr   = (int*)ws;    ws += 8 * 4;                  // work-steal counters
    int*   off   = (int*)ws;    ws += (size_t)(N + 4) * 4;
    int*   parts = (int*)ws;    ws += 1024 * 4;
    unsigned short* rank = (unsigned short*)ws;  ws += (size_t)((E + 7) & ~7) * 2;
    int*   eidx  = (int*)ws;    // E ints

    const int nScanBlocks = (N + SCAN_BLK - 1) / SCAN_BLK;
    const int edgeBlocks = (E + 1023) / 1024;
    const int nDegChunks = (E + DEG_CHUNK - 1) / DEG_CHUNK;  // 98
    const int nTiles = (N + 127) / 128;                      // 782

    k_prelude<<<16 + (N + 255) / 256, 256, 0, stream>>>(W, Wb, cnt, ctr, N);

    megaX<<<1024, 256, 0, stream>>>(x, Wb, g, N, dst, cnt, rank, E,
                                    ctr, nDegChunks, nTiles);

    k_scan1<<<nScanBlocks, SCAN_BLK, 0, stream>>>(cnt, off, parts, dinv, N);
    k_scan2<<<1, 256, 0, stream>>>(parts, nScanBlocks);

    k_fill<<<edgeBlocks, 256, 0, stream>>>(src, dst, off, parts, rank, eidx, E);

    k_agg<<<(N + 31) / 32, 256, 0, stream>>>(g, dinv, b, off, parts, eidx, out, N);
}

// Round 13
// 220.949 us; speedup vs baseline: 2.0520x; 1.0706x over previous
//
#include <hip/hip_runtime.h>
#include <hip/hip_bf16.h>

#define F_IN 512
#define NCLS 64
#define SCAN_BLK 512

typedef __attribute__((ext_vector_type(8))) short short8;
typedef __attribute__((ext_vector_type(4))) float f32x4;
typedef __attribute__((ext_vector_type(4))) int i32x4;
typedef __attribute__((ext_vector_type(4))) unsigned short u16x4;

static __device__ __forceinline__ short bf16_of(float f) {
    __hip_bfloat16 h = __float2bfloat16(f);
    short s;
    __builtin_memcpy(&s, &h, 2);
    return s;
}
static __device__ __forceinline__ float b2f(short s) {
    unsigned u = ((unsigned)(unsigned short)s) << 16;
    float f;
    __builtin_memcpy(&f, &u, 4);
    return f;
}

// ---------------- prelude: wconvert (blocks 0..15) + zero cnt (rest) ----------------
__global__ __launch_bounds__(256) void k_prelude(const float* __restrict__ W,
                                                 short* __restrict__ Wb,
                                                 int* __restrict__ cnt, int n) {
    const int bid = blockIdx.x;
    if (bid < 16) {
        int t = bid * 256 + threadIdx.x;  // 4096 total
        int c = t >> 10;
        int kk = (t >> 6) & 15;
        int l = t & 63;
        short8 v;
#pragma unroll
        for (int j = 0; j < 8; ++j) {
            v[j] = bf16_of(W[(size_t)(kk * 32 + (l >> 4) * 8 + j) * NCLS + c * 16 + (l & 15)]);
        }
        reinterpret_cast<short8*>(Wb)[t] = v;
    } else {
        int i = (bid - 16) * 256 + threadIdx.x;
        if (i < n) cnt[i] = 0;
    }
}

// ---------------- deg_count: 4 edges/thread, returning atomics, isolated pass ----------------
__global__ __launch_bounds__(256) void k_deg(const int* __restrict__ dst,
                                             int* __restrict__ cnt,
                                             unsigned short* __restrict__ rank, int e) {
    int base = (blockIdx.x * 256 + threadIdx.x) * 4;
    if (base + 4 <= e) {
        i32x4 d4 = __builtin_nontemporal_load(reinterpret_cast<const i32x4*>(dst + base));
        u16x4 r;
        r[0] = (unsigned short)atomicAdd(&cnt[d4[0]], 1);
        r[1] = (unsigned short)atomicAdd(&cnt[d4[1]], 1);
        r[2] = (unsigned short)atomicAdd(&cnt[d4[2]], 1);
        r[3] = (unsigned short)atomicAdd(&cnt[d4[3]], 1);
        *reinterpret_cast<u16x4*>(rank + base) = r;
    } else {
        for (int i = base; i < e; ++i)
            rank[i] = (unsigned short)atomicAdd(&cnt[dst[i]], 1);
    }
}

// ---------------- scan1: block-local exclusive scan + dinv; off[n] sentinel ----------------
__global__ __launch_bounds__(SCAN_BLK) void k_scan1(const int* __restrict__ cnt,
                                                    int* __restrict__ off,
                                                    int* __restrict__ partials,
                                                    float* __restrict__ dinv, int n) {
    __shared__ int s[SCAN_BLK];
    int tid = threadIdx.x;
    int i = blockIdx.x * SCAN_BLK + tid;
    int v = (i < n) ? cnt[i] : 0;
    if (i < n) dinv[i] = rsqrtf(1.0f + (float)v);
    s[tid] = v;
    __syncthreads();
#pragma unroll
    for (int d = 1; d < SCAN_BLK; d <<= 1) {
        int t = (tid >= d) ? s[tid - d] : 0;
        __syncthreads();
        s[tid] += t;
        __syncthreads();
    }
    if (i < n) off[i] = s[tid] - v;       // block-local exclusive
    if (i == n - 1) off[n] = s[tid];      // block-local inclusive sentinel
    if (tid == SCAN_BLK - 1) partials[blockIdx.x] = s[tid];
}

__global__ __launch_bounds__(256) void k_scan2(int* __restrict__ partials, int p) {
    __shared__ int s[256];
    int tid = threadIdx.x;
    int v = (tid < p) ? partials[tid] : 0;
    s[tid] = v;
    __syncthreads();
#pragma unroll
    for (int d = 1; d < 256; d <<= 1) {
        int t = (tid >= d) ? s[tid - d] : 0;
        __syncthreads();
        s[tid] += t;
        __syncthreads();
    }
    if (tid < p) partials[tid] = s[tid] - v;  // exclusive
}

// ---------------- MFMA GEMM: g = bf16((x @ W) * dinv[row]), 32 rows/wave ----------------
__global__ __launch_bounds__(256) void k_gemm(const float* __restrict__ x,
                                              const short* __restrict__ Wb,
                                              const float* __restrict__ dinv,
                                              short* __restrict__ g, int n) {
    const int wave = threadIdx.x >> 6;
    const int lane = threadIdx.x & 63;
    const int rowTile = blockIdx.x * 128 + wave * 32;

    int r0 = rowTile + (lane & 15);
    int r1 = r0 + 16;
    if (r0 > n - 1) r0 = n - 1;
    if (r1 > n - 1) r1 = n - 1;
    const float* xr0 = x + (size_t)r0 * F_IN + ((lane >> 4) * 8);
    const float* xr1 = x + (size_t)r1 * F_IN + ((lane >> 4) * 8);

    const short8* wb8 = reinterpret_cast<const short8*>(Wb);

    f32x4 acc[2][4];
#pragma unroll
    for (int h = 0; h < 2; ++h)
#pragma unroll
        for (int c = 0; c < 4; ++c) acc[h][c] = {0.f, 0.f, 0.f, 0.f};

#pragma unroll 4
    for (int kk = 0; kk < 16; ++kk) {
        f32x4 p0 = __builtin_nontemporal_load(reinterpret_cast<const f32x4*>(xr0 + kk * 32));
        f32x4 p1 = __builtin_nontemporal_load(reinterpret_cast<const f32x4*>(xr0 + kk * 32 + 4));
        f32x4 q0 = __builtin_nontemporal_load(reinterpret_cast<const f32x4*>(xr1 + kk * 32));
        f32x4 q1 = __builtin_nontemporal_load(reinterpret_cast<const f32x4*>(xr1 + kk * 32 + 4));
        short8 a0, a1;
        a0[0] = bf16_of(p0[0]); a0[1] = bf16_of(p0[1]);
        a0[2] = bf16_of(p0[2]); a0[3] = bf16_of(p0[3]);
        a0[4] = bf16_of(p1[0]); a0[5] = bf16_of(p1[1]);
        a0[6] = bf16_of(p1[2]); a0[7] = bf16_of(p1[3]);
        a1[0] = bf16_of(q0[0]); a1[1] = bf16_of(q0[1]);
        a1[2] = bf16_of(q0[2]); a1[3] = bf16_of(q0[3]);
        a1[4] = bf16_of(q1[0]); a1[5] = bf16_of(q1[1]);
        a1[6] = bf16_of(q1[2]); a1[7] = bf16_of(q1[3]);
        short8 b0 = wb8[(0 * 16 + kk) * 64 + lane];
        short8 b1 = wb8[(1 * 16 + kk) * 64 + lane];
        short8 b2 = wb8[(2 * 16 + kk) * 64 + lane];
        short8 b3 = wb8[(3 * 16 + kk) * 64 + lane];
        acc[0][0] = __builtin_amdgcn_mfma_f32_16x16x32_bf16(a0, b0, acc[0][0], 0, 0, 0);
        acc[0][1] = __builtin_amdgcn_mfma_f32_16x16x32_bf16(a0, b1, acc[0][1], 0, 0, 0);
        acc[0][2] = __builtin_amdgcn_mfma_f32_16x16x32_bf16(a0, b2, acc[0][2], 0, 0, 0);
        acc[0][3] = __builtin_amdgcn_mfma_f32_16x16x32_bf16(a0, b3, acc[0][3], 0, 0, 0);
        acc[1][0] = __builtin_amdgcn_mfma_f32_16x16x32_bf16(a1, b0, acc[1][0], 0, 0, 0);
        acc[1][1] = __builtin_amdgcn_mfma_f32_16x16x32_bf16(a1, b1, acc[1][1], 0, 0, 0);
        acc[1][2] = __builtin_amdgcn_mfma_f32_16x16x32_bf16(a1, b2, acc[1][2], 0, 0, 0);
        acc[1][3] = __builtin_amdgcn_mfma_f32_16x16x32_bf16(a1, b3, acc[1][3], 0, 0, 0);
    }

    const int col = lane & 15;
#pragma unroll
    for (int h = 0; h < 2; ++h) {
        const int rbase = rowTile + h * 16 + (lane >> 4) * 4;
#pragma unroll
        for (int j = 0; j < 4; ++j) {
            int r = rbase + j;
            if (r < n) {
                float dv = dinv[r];
                short* go = g + (size_t)r * NCLS + col;
                go[0]  = bf16_of(acc[h][0][j] * dv);
                go[16] = bf16_of(acc[h][1][j] * dv);
                go[32] = bf16_of(acc[h][2][j] * dv);
                go[48] = bf16_of(acc[h][3][j] * dv);
            }
        }
    }
}

// ---------------- fill CSR — NO atomics, 4 edges/thread ----------------
__global__ __launch_bounds__(256) void k_fill(const int* __restrict__ src,
                                              const int* __restrict__ dst,
                                              const int* __restrict__ off,
                                              const int* __restrict__ parts,
                                              const unsigned short* __restrict__ rank,
                                              int* __restrict__ eidx, int e) {
    int base = (blockIdx.x * 256 + threadIdx.x) * 4;
    if (base + 4 <= e) {
        i32x4 s4 = __builtin_nontemporal_load(reinterpret_cast<const i32x4*>(src + base));
        i32x4 d4 = __builtin_nontemporal_load(reinterpret_cast<const i32x4*>(dst + base));
        u16x4 r4 = __builtin_nontemporal_load(reinterpret_cast<const u16x4*>(rank + base));
        eidx[off[d4[0]] + parts[d4[0] >> 9] + r4[0]] = s4[0];
        eidx[off[d4[1]] + parts[d4[1] >> 9] + r4[1]] = s4[1];
        eidx[off[d4[2]] + parts[d4[2] >> 9] + r4[2]] = s4[2];
        eidx[off[d4[3]] + parts[d4[3] >> 9] + r4[3]] = s4[3];
    } else {
        for (int i = base; i < e; ++i)
            eidx[off[dst[i]] + parts[dst[i] >> 9] + rank[i]] = src[i];
    }
}

// ---------------- fused gather + bias + log_softmax (g pre-scaled by dinv[src]) ----------------
// 8 nodes per wave: 8-lane sub-group per node; lane handles 8 channels (short8 = 16B).
__global__ __launch_bounds__(256) void k_agg(const short* __restrict__ g,
                                             const float* __restrict__ dinv,
                                             const float* __restrict__ bvec,
                                             const int* __restrict__ off,
                                             const int* __restrict__ parts,
                                             const int* __restrict__ eidx,
                                             float* __restrict__ out, int n) {
    const int wave = threadIdx.x >> 6;
    const int lane = threadIdx.x & 63;
    const int grp = lane >> 3;   // node sub-group 0..7
    const int li = lane & 7;     // channels li*8 .. li*8+7
    const int node = (blockIdx.x * 4 + wave) * 8 + grp;
    if (node >= n) return;

    const int s0 = off[node] + parts[node >> 9];
    const int np1 = node + 1;
    const int s1 = off[np1] + parts[(np1 == n ? n - 1 : np1) >> 9];

    const short8* g8 = reinterpret_cast<const short8*>(g);  // 8 short8 per row

    float acc[8];
    {
        short8 v = g8[(size_t)node * 8 + li];
#pragma unroll
        for (int c = 0; c < 8; ++c) acc[c] = b2f(v[c]);
    }

    int t = s0;
    for (; t + 8 <= s1; t += 8) {
        int sidx[8];
#pragma unroll
        for (int u = 0; u < 8; ++u) sidx[u] = eidx[t + u];
        short8 vv[8];
#pragma unroll
        for (int u = 0; u < 8; ++u) vv[u] = g8[(size_t)sidx[u] * 8 + li];
#pragma unroll
        for (int c = 0; c < 8; ++c)
            acc[c] += ((b2f(vv[0][c]) + b2f(vv[1][c])) + (b2f(vv[2][c]) + b2f(vv[3][c]))) +
                      ((b2f(vv[4][c]) + b2f(vv[5][c])) + (b2f(vv[6][c]) + b2f(vv[7][c])));
    }
    for (; t + 4 <= s1; t += 4) {
        int sa = eidx[t], sb = eidx[t + 1], sc = eidx[t + 2], sd = eidx[t + 3];
        short8 va = g8[(size_t)sa * 8 + li];
        short8 vb = g8[(size_t)sb * 8 + li];
        short8 vc = g8[(size_t)sc * 8 + li];
        short8 vd = g8[(size_t)sd * 8 + li];
#pragma unroll
        for (int c = 0; c < 8; ++c)
            acc[c] += (b2f(va[c]) + b2f(vb[c])) + (b2f(vc[c]) + b2f(vd[c]));
    }
    for (; t < s1; ++t) {
        int sa = eidx[t];
        short8 va = g8[(size_t)sa * 8 + li];
#pragma unroll
        for (int c = 0; c < 8; ++c) acc[c] += b2f(va[c]);
    }

    const float dn = dinv[node];
    const float4 b0 = reinterpret_cast<const float4*>(bvec)[li * 2];
    const float4 b1 = reinterpret_cast<const float4*>(bvec)[li * 2 + 1];
    float v[8];
    v[0] = acc[0] * dn + b0.x; v[1] = acc[1] * dn + b0.y;
    v[2] = acc[2] * dn + b0.z; v[3] = acc[3] * dn + b0.w;
    v[4] = acc[4] * dn + b1.x; v[5] = acc[5] * dn + b1.y;
    v[6] = acc[6] * dn + b1.z; v[7] = acc[7] * dn + b1.w;

    float m = v[0];
#pragma unroll
    for (int c = 1; c < 8; ++c) m = fmaxf(m, v[c]);
#pragma unroll
    for (int o = 1; o < 8; o <<= 1) m = fmaxf(m, __shfl_xor(m, o));

    float ex = 0.f;
#pragma unroll
    for (int c = 0; c < 8; ++c) ex += __expf(v[c] - m);
#pragma unroll
    for (int o = 1; o < 8; o <<= 1) ex += __shfl_xor(ex, o);
    const float lg = m + __logf(ex);

    f32x4 r0, r1;
    r0[0] = v[0] - lg; r0[1] = v[1] - lg; r0[2] = v[2] - lg; r0[3] = v[3] - lg;
    r1[0] = v[4] - lg; r1[1] = v[5] - lg; r1[2] = v[6] - lg; r1[3] = v[7] - lg;
    f32x4* o4 = reinterpret_cast<f32x4*>(out + (size_t)node * NCLS);
    __builtin_nontemporal_store(r0, o4 + li * 2);
    __builtin_nontemporal_store(r1, o4 + li * 2 + 1);
}

extern "C" void kernel_launch(void* const* d_in, const int* in_sizes, int n_in,
                              void* d_out, int out_size, void* d_ws, size_t ws_size,
                              hipStream_t stream) {
    const float* x = (const float*)d_in[0];       // [N, 512]
    const float* W = (const float*)d_in[1];       // [512, 64]
    const float* b = (const float*)d_in[2];       // [64]
    const int* edge_index = (const int*)d_in[3];  // [2, E]

    const int N = in_sizes[0] / F_IN;
    const int E = in_sizes[3] / 2;
    const int* src = edge_index;
    const int* dst = edge_index + E;

    float* out = (float*)d_out;  // [N, 64]

    // workspace layout (16B-aligned pieces first)
    char* ws = (char*)d_ws;
    short* g     = (short*)ws;  ws += (size_t)N * NCLS * 2;   // 12.8 MB bf16
    short* Wb    = (short*)ws;  ws += 4096 * 16;              // 64 KB
    float* dinv  = (float*)ws;  ws += (size_t)N * 4;
    int*   cnt   = (int*)ws;    ws += (size_t)N * 4;
    int*   off   = (int*)ws;    ws += (size_t)(N + 4) * 4;
    int*   parts = (int*)ws;    ws += 1024 * 4;
    unsigned short* rank = (unsigned short*)ws;  ws += (size_t)((E + 7) & ~7) * 2;
    int*   eidx  = (int*)ws;    // E ints

    const int nScanBlocks = (N + SCAN_BLK - 1) / SCAN_BLK;
    const int edgeBlocks = (E + 1023) / 1024;

    k_prelude<<<16 + (N + 255) / 256, 256, 0, stream>>>(W, Wb, cnt, N);

    k_deg<<<edgeBlocks, 256, 0, stream>>>(dst, cnt, rank, E);

    k_scan1<<<nScanBlocks, SCAN_BLK, 0, stream>>>(cnt, off, parts, dinv, N);
    k_scan2<<<1, 256, 0, stream>>>(parts, nScanBlocks);

    k_gemm<<<(N + 127) / 128, 256, 0, stream>>>(x, Wb, dinv, g, N);

    k_fill<<<edgeBlocks, 256, 0, stream>>>(src, dst, off, parts, rank, eidx, E);

    k_agg<<<(N + 31) / 32, 256, 0, stream>>>(g, dinv, b, off, parts, eidx, out, N);
}

// Round 14
// 186.535 us; speedup vs baseline: 2.4306x; 1.1845x over previous
//
#include <hip/hip_runtime.h>
#include <hip/hip_bf16.h>

#define F_IN 512
#define NCLS 64
#define SCAN_BLK 512
#define CNT_STRIDE 16  // one counter per 64B line

typedef __attribute__((ext_vector_type(8))) short short8;
typedef __attribute__((ext_vector_type(4))) float f32x4;

static __device__ __forceinline__ short bf16_of(float f) {
    __hip_bfloat16 h = __float2bfloat16(f);
    short s;
    __builtin_memcpy(&s, &h, 2);
    return s;
}
static __device__ __forceinline__ float b2f(short s) {
    unsigned u = ((unsigned)(unsigned short)s) << 16;
    float f;
    __builtin_memcpy(&f, &u, 4);
    return f;
}

// ---------------- prelude: wconvert (blocks 0..15) + zero padded cnt (rest) ----------------
__global__ __launch_bounds__(256) void k_prelude(const float* __restrict__ W,
                                                 short* __restrict__ Wb,
                                                 int* __restrict__ cnt, int nWords) {
    const int bid = blockIdx.x;
    if (bid < 16) {
        int t = bid * 256 + threadIdx.x;  // 4096 total
        int c = t >> 10;
        int kk = (t >> 6) & 15;
        int l = t & 63;
        short8 v;
#pragma unroll
        for (int j = 0; j < 8; ++j) {
            v[j] = bf16_of(W[(size_t)(kk * 32 + (l >> 4) * 8 + j) * NCLS + c * 16 + (l & 15)]);
        }
        reinterpret_cast<short8*>(Wb)[t] = v;
    } else {
        int i = ((bid - 16) * 256 + threadIdx.x) * 4;
        if (i + 4 <= nWords) {
            *reinterpret_cast<int4*>(cnt + i) = make_int4(0, 0, 0, 0);
        } else {
            for (int k2 = i; k2 < nWords; ++k2) cnt[k2] = 0;
        }
    }
}

// ---------------- deg_count: 8 edges/thread, returning atomics on line-padded counters ----------------
__global__ __launch_bounds__(256) void k_deg(const int* __restrict__ dst,
                                             int* __restrict__ cnt,
                                             unsigned short* __restrict__ rank, int e) {
    int base = (blockIdx.x * 256 + threadIdx.x) * 8;
    if (base + 8 <= e) {
        int4 dA = *reinterpret_cast<const int4*>(dst + base);
        int4 dB = *reinterpret_cast<const int4*>(dst + base + 4);
        ushort4 rA, rB;
        rA.x = (unsigned short)atomicAdd(&cnt[dA.x * CNT_STRIDE], 1);
        rA.y = (unsigned short)atomicAdd(&cnt[dA.y * CNT_STRIDE], 1);
        rA.z = (unsigned short)atomicAdd(&cnt[dA.z * CNT_STRIDE], 1);
        rA.w = (unsigned short)atomicAdd(&cnt[dA.w * CNT_STRIDE], 1);
        rB.x = (unsigned short)atomicAdd(&cnt[dB.x * CNT_STRIDE], 1);
        rB.y = (unsigned short)atomicAdd(&cnt[dB.y * CNT_STRIDE], 1);
        rB.z = (unsigned short)atomicAdd(&cnt[dB.z * CNT_STRIDE], 1);
        rB.w = (unsigned short)atomicAdd(&cnt[dB.w * CNT_STRIDE], 1);
        *reinterpret_cast<ushort4*>(rank + base) = rA;
        *reinterpret_cast<ushort4*>(rank + base + 4) = rB;
    } else {
        for (int i = base; i < e; ++i)
            rank[i] = (unsigned short)atomicAdd(&cnt[dst[i] * CNT_STRIDE], 1);
    }
}

// ---------------- scan1: block-local exclusive scan + dinv; off[n] sentinel ----------------
__global__ __launch_bounds__(SCAN_BLK) void k_scan1(const int* __restrict__ cnt,
                                                    int* __restrict__ off,
                                                    int* __restrict__ partials,
                                                    float* __restrict__ dinv, int n) {
    __shared__ int s[SCAN_BLK];
    int tid = threadIdx.x;
    int i = blockIdx.x * SCAN_BLK + tid;
    int v = (i < n) ? cnt[i * CNT_STRIDE] : 0;
    if (i < n) dinv[i] = rsqrtf(1.0f + (float)v);
    s[tid] = v;
    __syncthreads();
#pragma unroll
    for (int d = 1; d < SCAN_BLK; d <<= 1) {
        int t = (tid >= d) ? s[tid - d] : 0;
        __syncthreads();
        s[tid] += t;
        __syncthreads();
    }
    if (i < n) off[i] = s[tid] - v;       // block-local exclusive
    if (i == n - 1) off[n] = s[tid];      // block-local inclusive sentinel
    if (tid == SCAN_BLK - 1) partials[blockIdx.x] = s[tid];
}

__global__ __launch_bounds__(256) void k_scan2(int* __restrict__ partials, int p) {
    __shared__ int s[256];
    int tid = threadIdx.x;
    int v = (tid < p) ? partials[tid] : 0;
    s[tid] = v;
    __syncthreads();
#pragma unroll
    for (int d = 1; d < 256; d <<= 1) {
        int t = (tid >= d) ? s[tid - d] : 0;
        __syncthreads();
        s[tid] += t;
        __syncthreads();
    }
    if (tid < p) partials[tid] = s[tid] - v;  // exclusive
}

// ---------------- fill CSR — NO atomics, 4 edges/thread ----------------
__global__ __launch_bounds__(256) void k_fill(const int* __restrict__ src,
                                              const int* __restrict__ dst,
                                              const int* __restrict__ off,
                                              const int* __restrict__ parts,
                                              const unsigned short* __restrict__ rank,
                                              int* __restrict__ eidx, int e) {
    int base = (blockIdx.x * 256 + threadIdx.x) * 4;
    if (base + 4 <= e) {
        int4 s4 = *reinterpret_cast<const int4*>(src + base);
        int4 d4 = *reinterpret_cast<const int4*>(dst + base);
        ushort4 r4 = *reinterpret_cast<const ushort4*>(rank + base);
        eidx[off[d4.x] + parts[d4.x >> 9] + r4.x] = s4.x;
        eidx[off[d4.y] + parts[d4.y >> 9] + r4.y] = s4.y;
        eidx[off[d4.z] + parts[d4.z >> 9] + r4.z] = s4.z;
        eidx[off[d4.w] + parts[d4.w >> 9] + r4.w] = s4.w;
    } else {
        for (int i = base; i < e; ++i)
            eidx[off[dst[i]] + parts[dst[i] >> 9] + rank[i]] = src[i];
    }
}

// ---------------- MFMA GEMM: g = bf16((x @ W) * dinv[row]), 32 rows/wave ----------------
__global__ __launch_bounds__(256) void k_gemm(const float* __restrict__ x,
                                              const short* __restrict__ Wb,
                                              const float* __restrict__ dinv,
                                              short* __restrict__ g, int n) {
    const int wave = threadIdx.x >> 6;
    const int lane = threadIdx.x & 63;
    const int rowTile = blockIdx.x * 128 + wave * 32;

    int r0 = rowTile + (lane & 15);
    int r1 = r0 + 16;
    if (r0 > n - 1) r0 = n - 1;
    if (r1 > n - 1) r1 = n - 1;
    const float* xr0 = x + (size_t)r0 * F_IN + ((lane >> 4) * 8);
    const float* xr1 = x + (size_t)r1 * F_IN + ((lane >> 4) * 8);

    const short8* wb8 = reinterpret_cast<const short8*>(Wb);

    f32x4 acc[2][4];
#pragma unroll
    for (int h = 0; h < 2; ++h)
#pragma unroll
        for (int c = 0; c < 4; ++c) acc[h][c] = {0.f, 0.f, 0.f, 0.f};

#pragma unroll 4
    for (int kk = 0; kk < 16; ++kk) {
        float4 p0 = *reinterpret_cast<const float4*>(xr0 + kk * 32);
        float4 p1 = *reinterpret_cast<const float4*>(xr0 + kk * 32 + 4);
        float4 q0 = *reinterpret_cast<const float4*>(xr1 + kk * 32);
        float4 q1 = *reinterpret_cast<const float4*>(xr1 + kk * 32 + 4);
        short8 a0, a1;
        a0[0] = bf16_of(p0.x); a0[1] = bf16_of(p0.y);
        a0[2] = bf16_of(p0.z); a0[3] = bf16_of(p0.w);
        a0[4] = bf16_of(p1.x); a0[5] = bf16_of(p1.y);
        a0[6] = bf16_of(p1.z); a0[7] = bf16_of(p1.w);
        a1[0] = bf16_of(q0.x); a1[1] = bf16_of(q0.y);
        a1[2] = bf16_of(q0.z); a1[3] = bf16_of(q0.w);
        a1[4] = bf16_of(q1.x); a1[5] = bf16_of(q1.y);
        a1[6] = bf16_of(q1.z); a1[7] = bf16_of(q1.w);
        short8 b0 = wb8[(0 * 16 + kk) * 64 + lane];
        short8 b1 = wb8[(1 * 16 + kk) * 64 + lane];
        short8 b2 = wb8[(2 * 16 + kk) * 64 + lane];
        short8 b3 = wb8[(3 * 16 + kk) * 64 + lane];
        acc[0][0] = __builtin_amdgcn_mfma_f32_16x16x32_bf16(a0, b0, acc[0][0], 0, 0, 0);
        acc[0][1] = __builtin_amdgcn_mfma_f32_16x16x32_bf16(a0, b1, acc[0][1], 0, 0, 0);
        acc[0][2] = __builtin_amdgcn_mfma_f32_16x16x32_bf16(a0, b2, acc[0][2], 0, 0, 0);
        acc[0][3] = __builtin_amdgcn_mfma_f32_16x16x32_bf16(a0, b3, acc[0][3], 0, 0, 0);
        acc[1][0] = __builtin_amdgcn_mfma_f32_16x16x32_bf16(a1, b0, acc[1][0], 0, 0, 0);
        acc[1][1] = __builtin_amdgcn_mfma_f32_16x16x32_bf16(a1, b1, acc[1][1], 0, 0, 0);
        acc[1][2] = __builtin_amdgcn_mfma_f32_16x16x32_bf16(a1, b2, acc[1][2], 0, 0, 0);
        acc[1][3] = __builtin_amdgcn_mfma_f32_16x16x32_bf16(a1, b3, acc[1][3], 0, 0, 0);
    }

    const int col = lane & 15;
#pragma unroll
    for (int h = 0; h < 2; ++h) {
        const int rbase = rowTile + h * 16 + (lane >> 4) * 4;
#pragma unroll
        for (int j = 0; j < 4; ++j) {
            int r = rbase + j;
            if (r < n) {
                float dv = dinv[r];
                short* go = g + (size_t)r * NCLS + col;
                go[0]  = bf16_of(acc[h][0][j] * dv);
                go[16] = bf16_of(acc[h][1][j] * dv);
                go[32] = bf16_of(acc[h][2][j] * dv);
                go[48] = bf16_of(acc[h][3][j] * dv);
            }
        }
    }
}

// ---------------- fused gather + bias + log_softmax (g pre-scaled by dinv[src]) ----------------
// 8 nodes per wave: 8-lane sub-group per node; lane handles 8 channels (short8 = 16B).
__global__ __launch_bounds__(256) void k_agg(const short* __restrict__ g,
                                             const float* __restrict__ dinv,
                                             const float* __restrict__ bvec,
                                             const int* __restrict__ off,
                                             const int* __restrict__ parts,
                                             const int* __restrict__ eidx,
                                             float* __restrict__ out, int n) {
    const int wave = threadIdx.x >> 6;
    const int lane = threadIdx.x & 63;
    const int grp = lane >> 3;   // node sub-group 0..7
    const int li = lane & 7;     // channels li*8 .. li*8+7
    const int node = (blockIdx.x * 4 + wave) * 8 + grp;
    if (node >= n) return;

    const int s0 = off[node] + parts[node >> 9];
    const int np1 = node + 1;
    const int s1 = off[np1] + parts[(np1 == n ? n - 1 : np1) >> 9];

    const short8* g8 = reinterpret_cast<const short8*>(g);  // 8 short8 per row

    float acc[8];
    {
        short8 v = g8[(size_t)node * 8 + li];
#pragma unroll
        for (int c = 0; c < 8; ++c) acc[c] = b2f(v[c]);
    }

    int t = s0;
    for (; t + 8 <= s1; t += 8) {
        int sidx[8];
#pragma unroll
        for (int u = 0; u < 8; ++u) sidx[u] = eidx[t + u];
        short8 vv[8];
#pragma unroll
        for (int u = 0; u < 8; ++u) vv[u] = g8[(size_t)sidx[u] * 8 + li];
#pragma unroll
        for (int c = 0; c < 8; ++c)
            acc[c] += ((b2f(vv[0][c]) + b2f(vv[1][c])) + (b2f(vv[2][c]) + b2f(vv[3][c]))) +
                      ((b2f(vv[4][c]) + b2f(vv[5][c])) + (b2f(vv[6][c]) + b2f(vv[7][c])));
    }
    for (; t + 4 <= s1; t += 4) {
        int sa = eidx[t], sb = eidx[t + 1], sc = eidx[t + 2], sd = eidx[t + 3];
        short8 va = g8[(size_t)sa * 8 + li];
        short8 vb = g8[(size_t)sb * 8 + li];
        short8 vc = g8[(size_t)sc * 8 + li];
        short8 vd = g8[(size_t)sd * 8 + li];
#pragma unroll
        for (int c = 0; c < 8; ++c)
            acc[c] += (b2f(va[c]) + b2f(vb[c])) + (b2f(vc[c]) + b2f(vd[c]));
    }
    for (; t < s1; ++t) {
        int sa = eidx[t];
        short8 va = g8[(size_t)sa * 8 + li];
#pragma unroll
        for (int c = 0; c < 8; ++c) acc[c] += b2f(va[c]);
    }

    const float dn = dinv[node];
    const float4 b0 = reinterpret_cast<const float4*>(bvec)[li * 2];
    const float4 b1 = reinterpret_cast<const float4*>(bvec)[li * 2 + 1];
    float v[8];
    v[0] = acc[0] * dn + b0.x; v[1] = acc[1] * dn + b0.y;
    v[2] = acc[2] * dn + b0.z; v[3] = acc[3] * dn + b0.w;
    v[4] = acc[4] * dn + b1.x; v[5] = acc[5] * dn + b1.y;
    v[6] = acc[6] * dn + b1.z; v[7] = acc[7] * dn + b1.w;

    float m = v[0];
#pragma unroll
    for (int c = 1; c < 8; ++c) m = fmaxf(m, v[c]);
#pragma unroll
    for (int o = 1; o < 8; o <<= 1) m = fmaxf(m, __shfl_xor(m, o));

    float ex = 0.f;
#pragma unroll
    for (int c = 0; c < 8; ++c) ex += __expf(v[c] - m);
#pragma unroll
    for (int o = 1; o < 8; o <<= 1) ex += __shfl_xor(ex, o);
    const float lg = m + __logf(ex);

    float4 r0, r1;
    r0.x = v[0] - lg; r0.y = v[1] - lg; r0.z = v[2] - lg; r0.w = v[3] - lg;
    r1.x = v[4] - lg; r1.y = v[5] - lg; r1.z = v[6] - lg; r1.w = v[7] - lg;
    float4* o4 = reinterpret_cast<float4*>(out + (size_t)node * NCLS);
    o4[li * 2] = r0;
    o4[li * 2 + 1] = r1;
}

extern "C" void kernel_launch(void* const* d_in, const int* in_sizes, int n_in,
                              void* d_out, int out_size, void* d_ws, size_t ws_size,
                              hipStream_t stream) {
    const float* x = (const float*)d_in[0];       // [N, 512]
    const float* W = (const float*)d_in[1];       // [512, 64]
    const float* b = (const float*)d_in[2];       // [64]
    const int* edge_index = (const int*)d_in[3];  // [2, E]

    const int N = in_sizes[0] / F_IN;
    const int E = in_sizes[3] / 2;
    const int* src = edge_index;
    const int* dst = edge_index + E;

    float* out = (float*)d_out;  // [N, 64]

    // workspace layout (16B-aligned pieces first)
    char* ws = (char*)d_ws;
    short* g     = (short*)ws;  ws += (size_t)N * NCLS * 2;          // 12.8 MB bf16
    short* Wb    = (short*)ws;  ws += 4096 * 16;                     // 64 KB
    float* dinv  = (float*)ws;  ws += (size_t)N * 4;
    int*   cnt   = (int*)ws;    ws += (size_t)N * CNT_STRIDE * 4;    // 6.4 MB line-padded
    int*   off   = (int*)ws;    ws += (size_t)(N + 4) * 4;
    int*   parts = (int*)ws;    ws += 1024 * 4;
    unsigned short* rank = (unsigned short*)ws;  ws += (size_t)((E + 7) & ~7) * 2;
    int*   eidx  = (int*)ws;    // E ints

    const int nWords = N * CNT_STRIDE;
    const int nScanBlocks = (N + SCAN_BLK - 1) / SCAN_BLK;
    const int fillBlocks = (E + 1023) / 1024;
    const int degBlocks = (E + 2047) / 2048;

    k_prelude<<<16 + (nWords / 4 + 255) / 256, 256, 0, stream>>>(W, Wb, cnt, nWords);

    k_deg<<<degBlocks, 256, 0, stream>>>(dst, cnt, rank, E);

    k_scan1<<<nScanBlocks, SCAN_BLK, 0, stream>>>(cnt, off, parts, dinv, N);
    k_scan2<<<1, 256, 0, stream>>>(parts, nScanBlocks);

    k_gemm<<<(N + 127) / 128, 256, 0, stream>>>(x, Wb, dinv, g, N);

    k_fill<<<fillBlocks, 256, 0, stream>>>(src, dst, off, parts, rank, eidx, E);

    k_agg<<<(N + 31) / 32, 256, 0, stream>>>(g, dinv, b, off, parts, eidx, out, N);
}